// Round 1
// baseline (554.275 us; speedup 1.0000x reference)
//
#include <hip/hip_runtime.h>
#include <hip/hip_bf16.h>
#include <cstdint>

typedef __attribute__((ext_vector_type(8))) short bf16x8;   // 8 bf16 (4 VGPRs)
typedef __attribute__((ext_vector_type(4))) float f32x4;    // MFMA C/D

#define BN_EPS 1e-5f

// ---------------------------------------------------------------------------
// prep1: V[o][j*96+c] = W1[o][j*96+c]*s1[j*96+c] - (j<12 ? W1[o][(j+1)*96+c]*s1[...] : 0)
//        b1eff[o] = conv1_b[o] + sum_i W1[o][i]*(beta1[i]-mean1[i]*s1[i])
// ---------------------------------------------------------------------------
__global__ __launch_bounds__(256) void prep1_kernel(
    const float* __restrict__ W1, const float* __restrict__ cb1,
    const float* __restrict__ g1, const float* __restrict__ be1,
    const float* __restrict__ mu1, const float* __restrict__ va1,
    __hip_bfloat16* __restrict__ V, float* __restrict__ b1e)
{
  int o = blockIdx.x;
  int t = threadIdx.x;
  const float* wrow = W1 + (size_t)o * 1248;
  float acc = 0.f;
  for (int i = t; i < 1248; i += 256) {
    float s = g1[i] * rsqrtf(va1[i] + BN_EPS);
    float w = wrow[i];
    acc += w * (be1[i] - mu1[i] * s);
    float g = w * s;
    float gn = 0.f;
    if (i < 1152) {  // 1248-96: has a next-ring partner
      float sn = g1[i + 96] * rsqrtf(va1[i + 96] + BN_EPS);
      gn = wrow[i + 96] * sn;
    }
    V[(size_t)o * 1248 + i] = __float2bfloat16(g - gn);
  }
  for (int d = 32; d > 0; d >>= 1) acc += __shfl_down(acc, d);
  __shared__ float red[4];
  int lane = t & 63, wv = t >> 6;
  if (lane == 0) red[wv] = acc;
  __syncthreads();
  if (t == 0) b1e[o] = cb1[o] + red[0] + red[1] + red[2] + red[3];
}

// ---------------------------------------------------------------------------
// prep2: W2eff[o][j] = W2[o][j]*s2[j];  b2eff[o] = conv2_b[o] + sum_j W2[o][j]*t2[j]
// ---------------------------------------------------------------------------
__global__ __launch_bounds__(256) void prep2_kernel(
    const float* __restrict__ W2, const float* __restrict__ cb2,
    const float* __restrict__ g2, const float* __restrict__ be2,
    const float* __restrict__ mu2, const float* __restrict__ va2,
    __hip_bfloat16* __restrict__ W2e, float* __restrict__ b2e)
{
  int o = blockIdx.x;
  int t = threadIdx.x;
  const float* wrow = W2 + (size_t)o * 512;
  float acc = 0.f;
  for (int j = t; j < 512; j += 256) {
    float s = g2[j] * rsqrtf(va2[j] + BN_EPS);
    float wv = wrow[j];
    acc += wv * (be2[j] - mu2[j] * s);
    W2e[(size_t)o * 512 + j] = __float2bfloat16(wv * s);
  }
  for (int d = 32; d > 0; d >>= 1) acc += __shfl_down(acc, d);
  __shared__ float red[4];
  int lane = t & 63, wv2 = t >> 6;
  if (lane == 0) red[wv2] = acc;
  __syncthreads();
  if (t == 0) b2e[o] = cb2[o] + red[0] + red[1] + red[2] + red[3];
}

// ---------------------------------------------------------------------------
// sat: one block per (b,c) plane. Exclusive SAT [129][129], zero row/col 0.
// LDS tile 128x128 fp32 = 64KB, XOR-swizzled (stride-128 would be 128-way
// bank conflict in the column scan).
// ---------------------------------------------------------------------------
__global__ __launch_bounds__(128) void sat_kernel(
    const float* __restrict__ x, float* __restrict__ SAT)
{
  int plane = blockIdx.x;
  const float* xp = x + (size_t)plane * 16384;
  __shared__ float tile[16384];
  int t = threadIdx.x;
  for (int i = t; i < 16384; i += 128) {
    int r = i >> 7, c = i & 127;
    tile[r * 128 + (c ^ (r & 31))] = xp[i];
  }
  __syncthreads();
  {  // row scan: thread = row
    float run = 0.f;
    int r = t;
    for (int c = 0; c < 128; ++c) {
      int a = r * 128 + (c ^ (r & 31));
      run += tile[a];
      tile[a] = run;
    }
  }
  __syncthreads();
  // column scan + global write: thread = column
  float* Sg = SAT + (size_t)plane * 16641;  // 129*129
  if (t == 0) Sg[0] = 0.f;
  Sg[t + 1] = 0.f;            // row 0
  Sg[(t + 1) * 129] = 0.f;    // col 0
  float run = 0.f;
  for (int r = 0; r < 128; ++r) {
    run += tile[r * 128 + (t ^ (r & 31))];
    Sg[(r + 1) * 129 + t + 1] = run;
  }
}

// ---------------------------------------------------------------------------
// feat: Hmat[(bL*16384+p)][j*96+c] = box_{2j+1}(x[bL][c]) at pixel p (bf16).
// Block = 64 x-contiguous pixels (same image row) x 4 channel-parallel.
// [64][96] LDS stage per j so global writes are coalesced 16B chunks.
// ---------------------------------------------------------------------------
__global__ __launch_bounds__(256) void feat_kernel(
    const float* __restrict__ SAT, __hip_bfloat16* __restrict__ Hmat)
{
  int blk = blockIdx.x;
  int bL = blk >> 8;        // local batch
  int tl = blk & 255;       // pixel tile within batch
  int p0 = tl * 64;
  int y = p0 >> 7;
  int x0 = p0 & 127;
  int tx = threadIdx.x & 63;
  int ty = threadIdx.x >> 6;
  int x = x0 + tx;
  __shared__ __align__(16) __hip_bfloat16 stage[64 * 96];
  size_t rowbase = ((size_t)bL * 16384 + p0) * 1248;

  for (int j = 0; j < 13; ++j) {
    int y1 = (y - j < 0) ? 0 : (y - j);
    int y2 = ((y + j > 127) ? 127 : (y + j)) + 1;
    int yo1 = y1 * 129, yo2 = y2 * 129;
    int x1 = (x - j < 0) ? 0 : (x - j);
    int x2 = ((x + j > 127) ? 127 : (x + j)) + 1;
    for (int cc = 0; cc < 24; ++cc) {
      int c = cc * 4 + ty;
      const float* S = SAT + (size_t)(bL * 96 + c) * 16641;
      float Bv = S[yo2 + x2] - S[yo1 + x2] - S[yo2 + x1] + S[yo1 + x1];
      stage[tx * 96 + c] = __float2bfloat16(Bv);
    }
    __syncthreads();
    // 64 rows x 96 bf16 = 768 chunks of 16B; 256 threads x 3
    for (int it = 0; it < 3; ++it) {
      int chunk = it * 256 + threadIdx.x;
      int row = chunk / 12;
      int off = (chunk % 12) * 8;
      uint4 v = *(const uint4*)(stage + row * 96 + off);
      *(uint4*)(Hmat + rowbase + (size_t)row * 1248 + j * 96 + off) = v;
    }
    __syncthreads();
  }
}

// ---------------------------------------------------------------------------
// gemm1: Y1[m][n] = bf16( relu( sum_k Hmat[m][k]*V[n][k] + b1eff[n] ) )
// 128x128 tile, BK=32, 4 waves (2x2), each wave 4x4 of 16x16x32 bf16 MFMA.
// LDS rows padded to 40 bf16 (no global_load_lds constraint this round).
// ---------------------------------------------------------------------------
__global__ __launch_bounds__(256) void gemm1_kernel(
    const __hip_bfloat16* __restrict__ A,    // [M][1248]
    const __hip_bfloat16* __restrict__ Bv,   // V [512][1248]
    const float* __restrict__ b1e,
    __hip_bfloat16* __restrict__ Y1)         // [M][512]
{
  const int K = 1248;
  int m0 = blockIdx.x * 128;
  int n0 = blockIdx.y * 128;
  int t = threadIdx.x;
  int lane = t & 63, wv = t >> 6;
  int wm = wv & 1, wn = wv >> 1;
  int lr = lane & 15, quad = lane >> 4;

  __shared__ __align__(16) __hip_bfloat16 As[128 * 40];
  __shared__ __align__(16) __hip_bfloat16 Bs[128 * 40];

  int srow = t >> 2;           // 0..63
  int soff = (t & 3) * 8;      // 0,8,16,24 (bf16 elems)
  const __hip_bfloat16* gA0 = A + (size_t)(m0 + srow) * K + soff;
  const __hip_bfloat16* gA1 = gA0 + (size_t)64 * K;
  const __hip_bfloat16* gB0 = Bv + (size_t)(n0 + srow) * K + soff;
  const __hip_bfloat16* gB1 = gB0 + (size_t)64 * K;
  __hip_bfloat16* sA0 = As + srow * 40 + soff;
  __hip_bfloat16* sA1 = sA0 + 64 * 40;
  __hip_bfloat16* sB0 = Bs + srow * 40 + soff;
  __hip_bfloat16* sB1 = sB0 + 64 * 40;

  f32x4 acc[4][4];
#pragma unroll
  for (int i = 0; i < 4; ++i)
#pragma unroll
    for (int jj = 0; jj < 4; ++jj) acc[i][jj] = (f32x4){0.f, 0.f, 0.f, 0.f};

  for (int k0 = 0; k0 < K; k0 += 32) {
    uint4 ra0 = *(const uint4*)(gA0 + k0);
    uint4 ra1 = *(const uint4*)(gA1 + k0);
    uint4 rb0 = *(const uint4*)(gB0 + k0);
    uint4 rb1 = *(const uint4*)(gB1 + k0);
    __syncthreads();  // previous iteration's LDS reads done
    *(uint4*)sA0 = ra0;
    *(uint4*)sA1 = ra1;
    *(uint4*)sB0 = rb0;
    *(uint4*)sB1 = rb1;
    __syncthreads();  // tiles visible

    bf16x8 af[4], bfr[4];
#pragma unroll
    for (int i = 0; i < 4; ++i)
      af[i] = *(const bf16x8*)(As + (wm * 64 + i * 16 + lr) * 40 + quad * 8);
#pragma unroll
    for (int jj = 0; jj < 4; ++jj)
      bfr[jj] = *(const bf16x8*)(Bs + (wn * 64 + jj * 16 + lr) * 40 + quad * 8);
#pragma unroll
    for (int i = 0; i < 4; ++i)
#pragma unroll
      for (int jj = 0; jj < 4; ++jj)
        acc[i][jj] = __builtin_amdgcn_mfma_f32_16x16x32_bf16(af[i], bfr[jj], acc[i][jj], 0, 0, 0);
  }

  // epilogue: +bias, relu, bf16 store. C/D: col=lane&15, row=quad*4+reg
#pragma unroll
  for (int jj = 0; jj < 4; ++jj) {
    int n = n0 + wn * 64 + jj * 16 + lr;
    float bias = b1e[n];
#pragma unroll
    for (int i = 0; i < 4; ++i) {
      int mbase = m0 + wm * 64 + i * 16 + quad * 4;
#pragma unroll
      for (int r = 0; r < 4; ++r) {
        float z = acc[i][jj][r] + bias;
        z = z > 0.f ? z : 0.f;
        Y1[(size_t)(mbase + r) * 512 + n] = __float2bfloat16(z);
      }
    }
  }
}

// ---------------------------------------------------------------------------
// gemm2: out[b][o2][p] = sum_k W2e[o2][k]*Y1[pix][k] + b2eff[o2]
// Computes C[o2][pixel] directly (A = W2e rows, B = Y1 rows) so NCHW stores
// are coalesced. No LDS: all frag loads are 64B-contiguous row segments;
// W2e (96KB) stays L2-hot.
// ---------------------------------------------------------------------------
__global__ __launch_bounds__(256) void gemm2_kernel(
    const __hip_bfloat16* __restrict__ Y1,   // [Mpix][512]
    const __hip_bfloat16* __restrict__ W2e,  // [96][512]
    const float* __restrict__ b2e,
    float* __restrict__ out, int b0)
{
  int lane = threadIdx.x & 63, wv = threadIdx.x >> 6;
  int lr = lane & 15, quad = lane >> 4;
  int pw = blockIdx.x * 256 + wv * 64;  // wave's pixel base (64 pixels)

  f32x4 acc[6][4];
#pragma unroll
  for (int im = 0; im < 6; ++im)
#pragma unroll
    for (int jn = 0; jn < 4; ++jn) acc[im][jn] = (f32x4){0.f, 0.f, 0.f, 0.f};

  for (int k0 = 0; k0 < 512; k0 += 32) {
    bf16x8 bfrag[4], afrag[6];
#pragma unroll
    for (int jn = 0; jn < 4; ++jn)
      bfrag[jn] = *(const bf16x8*)(Y1 + (size_t)(pw + jn * 16 + lr) * 512 + k0 + quad * 8);
#pragma unroll
    for (int im = 0; im < 6; ++im)
      afrag[im] = *(const bf16x8*)(W2e + (size_t)(im * 16 + lr) * 512 + k0 + quad * 8);
#pragma unroll
    for (int im = 0; im < 6; ++im)
#pragma unroll
      for (int jn = 0; jn < 4; ++jn)
        acc[im][jn] = __builtin_amdgcn_mfma_f32_16x16x32_bf16(afrag[im], bfrag[jn], acc[im][jn], 0, 0, 0);
  }

#pragma unroll
  for (int im = 0; im < 6; ++im) {
#pragma unroll
    for (int r = 0; r < 4; ++r) {
      int o2 = im * 16 + quad * 4 + r;
      float bias = b2e[o2];
#pragma unroll
      for (int jn = 0; jn < 4; ++jn) {
        int p = pw + jn * 16 + lr;
        out[((size_t)(b0 + (p >> 14)) * 96 + o2) * 16384 + (p & 16383)] =
            acc[im][jn][r] + bias;
      }
    }
  }
}

// ---------------------------------------------------------------------------
extern "C" void kernel_launch(void* const* d_in, const int* in_sizes, int n_in,
                              void* d_out, int out_size, void* d_ws, size_t ws_size,
                              hipStream_t stream)
{
  const float* x   = (const float*)d_in[0];
  const float* g1  = (const float*)d_in[1];
  const float* be1 = (const float*)d_in[2];
  const float* mu1 = (const float*)d_in[3];
  const float* va1 = (const float*)d_in[4];
  const float* W1  = (const float*)d_in[5];
  const float* cb1 = (const float*)d_in[6];
  const float* g2  = (const float*)d_in[7];
  const float* be2 = (const float*)d_in[8];
  const float* mu2 = (const float*)d_in[9];
  const float* va2 = (const float*)d_in[10];
  const float* W2  = (const float*)d_in[11];
  const float* cb2 = (const float*)d_in[12];
  float* out = (float*)d_out;

  char* w = (char*)d_ws;
  __hip_bfloat16* V   = (__hip_bfloat16*)w; w += (size_t)512 * 1248 * 2;
  __hip_bfloat16* W2e = (__hip_bfloat16*)w; w += (size_t)96 * 512 * 2;
  float* b1e = (float*)w; w += 2048;
  float* b2e = (float*)w; w += 512;
  size_t fixed = (size_t)(w - (char*)d_ws);

  const size_t satB = (size_t)96 * 16641 * 4;     // per-batch SAT bytes
  const size_t hB   = (size_t)16384 * 1248 * 2;   // per-batch Hmat bytes
  const size_t yB   = (size_t)16384 * 512 * 2;    // per-batch Y1 bytes
  // full-batch path needs ~258 MB of ws; else fall back to 4 sequential passes
  int nb = (ws_size >= fixed + 4 * (satB + hB + yB) + 4096) ? 4 : 1;

  float* SAT = (float*)w; w += (size_t)nb * satB;
  w = (char*)(((uintptr_t)w + 255) & ~(uintptr_t)255);
  __hip_bfloat16* Hm = (__hip_bfloat16*)w; w += (size_t)nb * hB;
  __hip_bfloat16* Y1 = (__hip_bfloat16*)w;

  prep1_kernel<<<512, 256, 0, stream>>>(W1, cb1, g1, be1, mu1, va1, V, b1e);
  prep2_kernel<<<96, 256, 0, stream>>>(W2, cb2, g2, be2, mu2, va2, W2e, b2e);

  for (int b0 = 0; b0 < 4; b0 += nb) {
    sat_kernel<<<nb * 96, 128, 0, stream>>>(x + (size_t)b0 * 96 * 16384, SAT);
    feat_kernel<<<nb * 256, 256, 0, stream>>>(SAT, Hm);
    gemm1_kernel<<<dim3(nb * 128, 4), 256, 0, stream>>>(Hm, V, b1e, Y1);
    gemm2_kernel<<<nb * 64, 256, 0, stream>>>(Y1, W2e, b2e, out, b0);
  }
}

// Round 2
// 504.911 us; speedup vs baseline: 1.0978x; 1.0978x over previous
//
#include <hip/hip_runtime.h>
#include <hip/hip_bf16.h>
#include <cstdint>

typedef __attribute__((ext_vector_type(8))) short bf16x8;   // 8 bf16 (4 VGPRs)
typedef __attribute__((ext_vector_type(4))) float f32x4;    // MFMA C/D

#define BN_EPS 1e-5f
#define GLOBAL_AS __attribute__((address_space(1)))
#define LDS_AS __attribute__((address_space(3)))

__device__ __forceinline__ void load_lds16(const __hip_bfloat16* g, __hip_bfloat16* l) {
  // async global->LDS, 16B/lane; LDS dest = uniform base + lane*16
  __builtin_amdgcn_global_load_lds((const GLOBAL_AS uint32_t*)g, (LDS_AS uint32_t*)l, 16, 0, 0);
}

// ---------------------------------------------------------------------------
// prep1: fold BN1 + ring telescoping into V (box-feature weights), b1eff.
// ---------------------------------------------------------------------------
__global__ __launch_bounds__(256) void prep1_kernel(
    const float* __restrict__ W1, const float* __restrict__ cb1,
    const float* __restrict__ g1, const float* __restrict__ be1,
    const float* __restrict__ mu1, const float* __restrict__ va1,
    __hip_bfloat16* __restrict__ V, float* __restrict__ b1e)
{
  int o = blockIdx.x;
  int t = threadIdx.x;
  const float* wrow = W1 + (size_t)o * 1248;
  float acc = 0.f;
  for (int i = t; i < 1248; i += 256) {
    float s = g1[i] * rsqrtf(va1[i] + BN_EPS);
    float w = wrow[i];
    acc += w * (be1[i] - mu1[i] * s);
    float g = w * s;
    float gn = 0.f;
    if (i < 1152) {  // has a next-ring partner
      float sn = g1[i + 96] * rsqrtf(va1[i + 96] + BN_EPS);
      gn = wrow[i + 96] * sn;
    }
    V[(size_t)o * 1248 + i] = __float2bfloat16(g - gn);
  }
  for (int d = 32; d > 0; d >>= 1) acc += __shfl_down(acc, d);
  __shared__ float red[4];
  int lane = t & 63, wv = t >> 6;
  if (lane == 0) red[wv] = acc;
  __syncthreads();
  if (t == 0) b1e[o] = cb1[o] + red[0] + red[1] + red[2] + red[3];
}

// ---------------------------------------------------------------------------
// prep2: fold BN2 into W2eff, b2eff.
// ---------------------------------------------------------------------------
__global__ __launch_bounds__(256) void prep2_kernel(
    const float* __restrict__ W2, const float* __restrict__ cb2,
    const float* __restrict__ g2, const float* __restrict__ be2,
    const float* __restrict__ mu2, const float* __restrict__ va2,
    __hip_bfloat16* __restrict__ W2e, float* __restrict__ b2e)
{
  int o = blockIdx.x;
  int t = threadIdx.x;
  const float* wrow = W2 + (size_t)o * 512;
  float acc = 0.f;
  for (int j = t; j < 512; j += 256) {
    float s = g2[j] * rsqrtf(va2[j] + BN_EPS);
    float wv = wrow[j];
    acc += wv * (be2[j] - mu2[j] * s);
    W2e[(size_t)o * 512 + j] = __float2bfloat16(wv * s);
  }
  for (int d = 32; d > 0; d >>= 1) acc += __shfl_down(acc, d);
  __shared__ float red[4];
  int lane = t & 63, wv2 = t >> 6;
  if (lane == 0) red[wv2] = acc;
  __syncthreads();
  if (t == 0) b2e[o] = cb2[o] + red[0] + red[1] + red[2] + red[3];
}

// ---------------------------------------------------------------------------
// sat: one block per (b,c) plane. Exclusive SAT [129][129].
// ---------------------------------------------------------------------------
__global__ __launch_bounds__(128) void sat_kernel(
    const float* __restrict__ x, float* __restrict__ SAT)
{
  int plane = blockIdx.x;
  const float* xp = x + (size_t)plane * 16384;
  __shared__ float tile[16384];
  int t = threadIdx.x;
  for (int i = t; i < 16384; i += 128) {
    int r = i >> 7, c = i & 127;
    tile[r * 128 + (c ^ (r & 31))] = xp[i];
  }
  __syncthreads();
  {  // row scan: thread = row
    float run = 0.f;
    int r = t;
    for (int c = 0; c < 128; ++c) {
      int a = r * 128 + (c ^ (r & 31));
      run += tile[a];
      tile[a] = run;
    }
  }
  __syncthreads();
  float* Sg = SAT + (size_t)plane * 16641;  // 129*129
  if (t == 0) Sg[0] = 0.f;
  Sg[t + 1] = 0.f;            // row 0
  Sg[(t + 1) * 129] = 0.f;    // col 0
  float run = 0.f;
  for (int r = 0; r < 128; ++r) {
    run += tile[r * 128 + (t ^ (r & 31))];
    Sg[(r + 1) * 129 + t + 1] = run;
  }
}

// ---------------------------------------------------------------------------
// feat v2: Hmat[(bL*16384+p)][j*96+c] = box_{2j+1}(x[bL][c]) at pixel p.
// Block = (batch, image row y, channel half). j outer; per (j, 8-ch group)
// each thread does 16 independent coalesced tap loads -> conflict-free
// stage[c][x] -> per-j write-out in 96B-contiguous segments.
// ---------------------------------------------------------------------------
__global__ __launch_bounds__(256) void feat_kernel(
    const float* __restrict__ SAT, __hip_bfloat16* __restrict__ Hmat)
{
  int blk = blockIdx.x;
  int ch = blk & 1;            // channel half: c0 = 0 or 48
  int y  = (blk >> 1) & 127;
  int bL = blk >> 8;
  int c0 = ch * 48;
  int t = threadIdx.x;
  int tx = t & 127;            // pixel x
  int tc = t >> 7;             // 0/1 -> +0/+4 within the 8-ch group

  __shared__ __align__(16) __hip_bfloat16 stage[48 * 129];  // [c_local][x], pad->conflict-free

  const float* Sb = SAT + (size_t)(bL * 96 + c0) * 16641;
  size_t rowbase = ((size_t)bL * 16384 + (size_t)y * 128) * 1248;

  for (int j = 0; j < 13; ++j) {
    int y1 = (y - j < 0) ? 0 : (y - j);
    int y2 = ((y + j > 127) ? 127 : (y + j)) + 1;
    int yo1 = y1 * 129, yo2 = y2 * 129;
    int x1 = (tx - j < 0) ? 0 : (tx - j);
    int x2 = ((tx + j > 127) ? 127 : (tx + j)) + 1;
    for (int cg = 0; cg < 6; ++cg) {
#pragma unroll
      for (int i = 0; i < 4; ++i) {
        int cl = cg * 8 + tc * 4 + i;  // 0..47
        const float* S = Sb + (size_t)cl * 16641;
        float v = S[yo2 + x2] - S[yo1 + x2] - S[yo2 + x1] + S[yo1 + x1];
        stage[cl * 129 + tx] = __float2bfloat16(v);
      }
    }
    __syncthreads();
    // write-out: 128 px * 6 chunks of 8 ch = 768 16B-chunks; lanes cover
    // 6 consecutive chunks per pixel -> 96B-contiguous global segments
#pragma unroll
    for (int it = 0; it < 3; ++it) {
      int q = it * 256 + t;          // 0..767
      int px = q / 6;
      int chk = q - px * 6;          // 0..5
      union { uint4 u; __hip_bfloat16 h[8]; } v;
#pragma unroll
      for (int i = 0; i < 8; ++i)
        v.h[i] = stage[(chk * 8 + i) * 129 + px];
      *(uint4*)(Hmat + rowbase + (size_t)px * 1248 + j * 96 + c0 + chk * 8) = v.u;
    }
    __syncthreads();
  }
}

// ---------------------------------------------------------------------------
// gemm1 (m97 structure): Y1[m][n] = bf16(relu(Hmat[m][:]*V[n][:]^T + b1e[n]))
// 128x128 tile, BK=32, global_load_lds width-16 into unpadded As/Bs[128][32].
// XCD-swizzled block order: 4 n-tiles of one m-tile stay on one XCD's L2.
// ---------------------------------------------------------------------------
__global__ __launch_bounds__(256) void gemm1_kernel(
    const __hip_bfloat16* __restrict__ A,    // [M][1248]
    const __hip_bfloat16* __restrict__ Bv,   // V [512][1248]
    const float* __restrict__ b1e,
    __hip_bfloat16* __restrict__ Y1)         // [M][512]
{
  const int K = 1248;
  int linear = blockIdx.x;
  int xcd = linear & 7;
  int slot = linear >> 3;
  int mtiles_per_xcd = (int)(gridDim.x >> 5);  // (gridDim.x/4 m-tiles)/8 xcds
  int ntile = slot & 3;
  int mtile = xcd * mtiles_per_xcd + (slot >> 2);
  int m0 = mtile * 128;
  int n0 = ntile * 128;
  int t = threadIdx.x;
  int lane = t & 63, wv = t >> 6;
  int wm = wv & 1, wn = wv >> 1;
  int lr = lane & 15, quad = lane >> 4;

  __shared__ __align__(16) __hip_bfloat16 As[128 * 32];
  __shared__ __align__(16) __hip_bfloat16 Bs[128 * 32];

  // staging: wave wv async-loads row groups {wv*16, (wv+4)*16} of A and B.
  // lane l -> row l>>2, col (l&3)*8  ==  LDS base + l*16B  (row-major [16][32])
  int srow = lane >> 2;
  int scol = (lane & 3) * 8;
  const __hip_bfloat16* gA0 = A + (size_t)(m0 + wv * 16 + srow) * K + scol;
  const __hip_bfloat16* gA1 = A + (size_t)(m0 + (wv + 4) * 16 + srow) * K + scol;
  const __hip_bfloat16* gB0 = Bv + (size_t)(n0 + wv * 16 + srow) * K + scol;
  const __hip_bfloat16* gB1 = Bv + (size_t)(n0 + (wv + 4) * 16 + srow) * K + scol;
  __hip_bfloat16* lA0 = As + (wv * 16) * 32;
  __hip_bfloat16* lA1 = As + ((wv + 4) * 16) * 32;
  __hip_bfloat16* lB0 = Bs + (wv * 16) * 32;
  __hip_bfloat16* lB1 = Bs + ((wv + 4) * 16) * 32;

  f32x4 acc[4][4];
#pragma unroll
  for (int i = 0; i < 4; ++i)
#pragma unroll
    for (int jj = 0; jj < 4; ++jj) acc[i][jj] = (f32x4){0.f, 0.f, 0.f, 0.f};

  for (int k0 = 0; k0 < K; k0 += 32) {
    __syncthreads();  // previous iteration's LDS reads done
    load_lds16(gA0 + k0, lA0);
    load_lds16(gA1 + k0, lA1);
    load_lds16(gB0 + k0, lB0);
    load_lds16(gB1 + k0, lB1);
    __syncthreads();  // staging drained (compiler emits vmcnt(0) before barrier)

    bf16x8 af[4], bfr[4];
#pragma unroll
    for (int i = 0; i < 4; ++i)
      af[i] = *(const bf16x8*)(As + (wm * 64 + i * 16 + lr) * 32 + quad * 8);
#pragma unroll
    for (int jj = 0; jj < 4; ++jj)
      bfr[jj] = *(const bf16x8*)(Bs + (wn * 64 + jj * 16 + lr) * 32 + quad * 8);
#pragma unroll
    for (int i = 0; i < 4; ++i)
#pragma unroll
      for (int jj = 0; jj < 4; ++jj)
        acc[i][jj] = __builtin_amdgcn_mfma_f32_16x16x32_bf16(af[i], bfr[jj], acc[i][jj], 0, 0, 0);
  }

  // epilogue: +bias, relu, bf16. C/D: col=lane&15, row=quad*4+reg
#pragma unroll
  for (int jj = 0; jj < 4; ++jj) {
    int n = n0 + wn * 64 + jj * 16 + lr;
    float bias = b1e[n];
#pragma unroll
    for (int i = 0; i < 4; ++i) {
      int mbase = m0 + wm * 64 + i * 16 + quad * 4;
#pragma unroll
      for (int r = 0; r < 4; ++r) {
        float z = acc[i][jj][r] + bias;
        z = z > 0.f ? z : 0.f;
        Y1[(size_t)(mbase + r) * 512 + n] = __float2bfloat16(z);
      }
    }
  }
}

// ---------------------------------------------------------------------------
// gemm2: out[b][o2][p] = W2e[o2][:] * Y1[pix][:] + b2e[o2]; C[o2][pixel]
// computed directly so NCHW stores are coalesced. LDS-free (W2e L2-hot).
// ---------------------------------------------------------------------------
__global__ __launch_bounds__(256) void gemm2_kernel(
    const __hip_bfloat16* __restrict__ Y1,   // [Mpix][512]
    const __hip_bfloat16* __restrict__ W2e,  // [96][512]
    const float* __restrict__ b2e,
    float* __restrict__ out, int b0)
{
  int lane = threadIdx.x & 63, wv = threadIdx.x >> 6;
  int lr = lane & 15, quad = lane >> 4;
  int pw = blockIdx.x * 256 + wv * 64;  // wave's pixel base

  f32x4 acc[6][4];
#pragma unroll
  for (int im = 0; im < 6; ++im)
#pragma unroll
    for (int jn = 0; jn < 4; ++jn) acc[im][jn] = (f32x4){0.f, 0.f, 0.f, 0.f};

  for (int k0 = 0; k0 < 512; k0 += 32) {
    bf16x8 bfrag[4], afrag[6];
#pragma unroll
    for (int jn = 0; jn < 4; ++jn)
      bfrag[jn] = *(const bf16x8*)(Y1 + (size_t)(pw + jn * 16 + lr) * 512 + k0 + quad * 8);
#pragma unroll
    for (int im = 0; im < 6; ++im)
      afrag[im] = *(const bf16x8*)(W2e + (size_t)(im * 16 + lr) * 512 + k0 + quad * 8);
#pragma unroll
    for (int im = 0; im < 6; ++im)
#pragma unroll
      for (int jn = 0; jn < 4; ++jn)
        acc[im][jn] = __builtin_amdgcn_mfma_f32_16x16x32_bf16(afrag[im], bfrag[jn], acc[im][jn], 0, 0, 0);
  }

#pragma unroll
  for (int im = 0; im < 6; ++im) {
#pragma unroll
    for (int r = 0; r < 4; ++r) {
      int o2 = im * 16 + quad * 4 + r;
      float bias = b2e[o2];
#pragma unroll
      for (int jn = 0; jn < 4; ++jn) {
        int p = pw + jn * 16 + lr;
        out[((size_t)(b0 + (p >> 14)) * 96 + o2) * 16384 + (p & 16383)] =
            acc[im][jn][r] + bias;
      }
    }
  }
}

// ---------------------------------------------------------------------------
extern "C" void kernel_launch(void* const* d_in, const int* in_sizes, int n_in,
                              void* d_out, int out_size, void* d_ws, size_t ws_size,
                              hipStream_t stream)
{
  const float* x   = (const float*)d_in[0];
  const float* g1  = (const float*)d_in[1];
  const float* be1 = (const float*)d_in[2];
  const float* mu1 = (const float*)d_in[3];
  const float* va1 = (const float*)d_in[4];
  const float* W1  = (const float*)d_in[5];
  const float* cb1 = (const float*)d_in[6];
  const float* g2  = (const float*)d_in[7];
  const float* be2 = (const float*)d_in[8];
  const float* mu2 = (const float*)d_in[9];
  const float* va2 = (const float*)d_in[10];
  const float* W2  = (const float*)d_in[11];
  const float* cb2 = (const float*)d_in[12];
  float* out = (float*)d_out;

  char* w = (char*)d_ws;
  __hip_bfloat16* V   = (__hip_bfloat16*)w; w += (size_t)512 * 1248 * 2;
  __hip_bfloat16* W2e = (__hip_bfloat16*)w; w += (size_t)96 * 512 * 2;
  float* b1e = (float*)w; w += 2048;
  float* b2e = (float*)w; w += 512;
  size_t fixed = (size_t)(w - (char*)d_ws);

  const size_t satB = (size_t)96 * 16641 * 4;     // per-batch SAT bytes
  const size_t hB   = (size_t)16384 * 1248 * 2;   // per-batch Hmat bytes
  const size_t yB   = (size_t)16384 * 512 * 2;    // per-batch Y1 bytes
  int nb = (ws_size >= fixed + 4 * (satB + hB + yB) + 4096) ? 4 : 1;

  float* SAT = (float*)w; w += (size_t)nb * satB;
  w = (char*)(((uintptr_t)w + 255) & ~(uintptr_t)255);
  __hip_bfloat16* Hm = (__hip_bfloat16*)w; w += (size_t)nb * hB;
  __hip_bfloat16* Y1 = (__hip_bfloat16*)w;

  prep1_kernel<<<512, 256, 0, stream>>>(W1, cb1, g1, be1, mu1, va1, V, b1e);
  prep2_kernel<<<96, 256, 0, stream>>>(W2, cb2, g2, be2, mu2, va2, W2e, b2e);

  for (int b0 = 0; b0 < 4; b0 += nb) {
    sat_kernel<<<nb * 96, 128, 0, stream>>>(x + (size_t)b0 * 96 * 16384, SAT);
    feat_kernel<<<nb * 256, 256, 0, stream>>>(SAT, Hm);
    gemm1_kernel<<<nb * 512, 256, 0, stream>>>(Hm, V, b1e, Y1);
    gemm2_kernel<<<nb * 64, 256, 0, stream>>>(Y1, W2e, b2e, out, b0);
  }
}

// Round 3
// 337.873 us; speedup vs baseline: 1.6405x; 1.4944x over previous
//
#include <hip/hip_runtime.h>
#include <hip/hip_bf16.h>
#include <cstdint>

typedef __attribute__((ext_vector_type(8))) short bf16x8;   // 8 bf16 (4 VGPRs)
typedef __attribute__((ext_vector_type(4))) float f32x4;    // MFMA C/D

#define BN_EPS 1e-5f
#define GLOBAL_AS __attribute__((address_space(1)))
#define LDS_AS __attribute__((address_space(3)))

__device__ __forceinline__ void load_lds16(const __hip_bfloat16* g, __hip_bfloat16* l) {
  // async global->LDS, 16B/lane; LDS dest = uniform base + lane*16
  __builtin_amdgcn_global_load_lds((const GLOBAL_AS uint32_t*)g, (LDS_AS uint32_t*)l, 16, 0, 0);
}

// ---------------------------------------------------------------------------
// prep1: fold BN1 + ring telescoping into V (box-feature weights), b1eff.
// ---------------------------------------------------------------------------
__global__ __launch_bounds__(256) void prep1_kernel(
    const float* __restrict__ W1, const float* __restrict__ cb1,
    const float* __restrict__ g1, const float* __restrict__ be1,
    const float* __restrict__ mu1, const float* __restrict__ va1,
    __hip_bfloat16* __restrict__ V, float* __restrict__ b1e)
{
  int o = blockIdx.x;
  int t = threadIdx.x;
  const float* wrow = W1 + (size_t)o * 1248;
  float acc = 0.f;
  for (int i = t; i < 1248; i += 256) {
    float s = g1[i] * rsqrtf(va1[i] + BN_EPS);
    float w = wrow[i];
    acc += w * (be1[i] - mu1[i] * s);
    float g = w * s;
    float gn = 0.f;
    if (i < 1152) {  // has a next-ring partner
      float sn = g1[i + 96] * rsqrtf(va1[i + 96] + BN_EPS);
      gn = wrow[i + 96] * sn;
    }
    V[(size_t)o * 1248 + i] = __float2bfloat16(g - gn);
  }
  for (int d = 32; d > 0; d >>= 1) acc += __shfl_down(acc, d);
  __shared__ float red[4];
  int lane = t & 63, wv = t >> 6;
  if (lane == 0) red[wv] = acc;
  __syncthreads();
  if (t == 0) b1e[o] = cb1[o] + red[0] + red[1] + red[2] + red[3];
}

// ---------------------------------------------------------------------------
// prep2: fold BN2 into W2eff, b2eff.
// ---------------------------------------------------------------------------
__global__ __launch_bounds__(256) void prep2_kernel(
    const float* __restrict__ W2, const float* __restrict__ cb2,
    const float* __restrict__ g2, const float* __restrict__ be2,
    const float* __restrict__ mu2, const float* __restrict__ va2,
    __hip_bfloat16* __restrict__ W2e, float* __restrict__ b2e)
{
  int o = blockIdx.x;
  int t = threadIdx.x;
  const float* wrow = W2 + (size_t)o * 512;
  float acc = 0.f;
  for (int j = t; j < 512; j += 256) {
    float s = g2[j] * rsqrtf(va2[j] + BN_EPS);
    float wv = wrow[j];
    acc += wv * (be2[j] - mu2[j] * s);
    W2e[(size_t)o * 512 + j] = __float2bfloat16(wv * s);
  }
  for (int d = 32; d > 0; d >>= 1) acc += __shfl_down(acc, d);
  __shared__ float red[4];
  int lane = t & 63, wv2 = t >> 6;
  if (lane == 0) red[wv2] = acc;
  __syncthreads();
  if (t == 0) b2e[o] = cb2[o] + red[0] + red[1] + red[2] + red[3];
}

// ---------------------------------------------------------------------------
// sat: one block per (b,c) plane. Exclusive SAT [129][132] (rows padded to
// 132 floats so every row is 16B-aligned for float4 loads in feat).
// ---------------------------------------------------------------------------
__global__ __launch_bounds__(128) void sat_kernel(
    const float* __restrict__ x, float* __restrict__ SAT)
{
  int plane = blockIdx.x;
  const float* xp = x + (size_t)plane * 16384;
  __shared__ float tile[16384];
  int t = threadIdx.x;
  for (int i = t; i < 16384; i += 128) {
    int r = i >> 7, c = i & 127;
    tile[r * 128 + (c ^ (r & 31))] = xp[i];
  }
  __syncthreads();
  {  // row scan: thread = row
    float run = 0.f;
    int r = t;
    for (int c = 0; c < 128; ++c) {
      int a = r * 128 + (c ^ (r & 31));
      run += tile[a];
      tile[a] = run;
    }
  }
  __syncthreads();
  float* Sg = SAT + (size_t)plane * 17028;  // 129*132
  Sg[t] = 0.f;                   // row 0, cols 0..127
  if (t < 4) Sg[128 + t] = 0.f;  // row 0, cols 128..131
  Sg[(t + 1) * 132] = 0.f;       // col 0, rows 1..128
  float run = 0.f;
  for (int r = 0; r < 128; ++r) {
    run += tile[r * 128 + (t ^ (r & 31))];
    Sg[(r + 1) * 132 + t + 1] = run;
  }
}

// ---------------------------------------------------------------------------
// feat v3: Hmat[(bL*16384+p)][j*96+c] = box_{2j+1}(x[bL][c]) at pixel p.
// Latency fix: per (j,ch) the 4 taps live on 2 SAT rows. Stage the row
// DIFFERENCE E[x]=S[y2][x]-S[y1][x] into LDS via float4 loads (16B granules,
// ~13 vmem/thread/j instead of 96 scalar dwords), taps become 2 LDS reads.
// XCD swizzle: blk&7 -> (batch, y-half) so each XCD's ~128 co-resident
// blocks share one ~4.5MB row window in its L2.
// ---------------------------------------------------------------------------
__global__ __launch_bounds__(256) void feat_kernel(
    const float* __restrict__ SAT, __hip_bfloat16* __restrict__ Hmat)
{
  int blk = blockIdx.x;
  int xcd = blk & 7;             // consecutive blocks round-robin XCDs
  int inner = blk >> 3;          // 0..127
  int bL = xcd >> 1;
  int yh = xcd & 1;
  int ch = inner & 1;            // channel half: c0 = 0 or 48
  int y  = yh * 64 + (inner >> 1);
  int c0 = ch * 48;
  int t = threadIdx.x;
  int tx = t & 127;              // pixel x
  int tc = t >> 7;               // 0/1: channels 0..23 / 24..47

  __shared__ __align__(16) float E[48 * 132];
  __shared__ __align__(16) __hip_bfloat16 stage[48 * 129];

  const float* Sb = SAT + (size_t)(bL * 96 + c0) * 17028;
  size_t rowbase = ((size_t)bL * 16384 + (size_t)y * 128) * 1248;

  for (int j = 0; j < 13; ++j) {
    int y1 = (y - j < 0) ? 0 : (y - j);
    int y2 = ((y + j > 127) ? 127 : (y + j)) + 1;
    // E-fill: 48 ch x 33 float4 chunks = 1584 tasks
    for (int idx = t; idx < 1584; idx += 256) {
      int cl = idx / 33;
      int ck = idx - cl * 33;
      const float* bp = Sb + (size_t)cl * 17028 + ck * 4;
      float4 a = *(const float4*)(bp + y2 * 132);
      float4 b = *(const float4*)(bp + y1 * 132);
      float* e = E + cl * 132 + ck * 4;
      e[0] = a.x - b.x; e[1] = a.y - b.y; e[2] = a.z - b.z; e[3] = a.w - b.w;
    }
    __syncthreads();
    int x1 = (tx - j < 0) ? 0 : (tx - j);
    int x2 = ((tx + j > 127) ? 127 : (tx + j)) + 1;
#pragma unroll
    for (int cc = 0; cc < 24; ++cc) {
      int cl = tc * 24 + cc;
      float v = E[cl * 132 + x2] - E[cl * 132 + x1];
      stage[cl * 129 + tx] = __float2bfloat16(v);
    }
    __syncthreads();
    // write-out: 128 px * 6 chunks of 8 ch = 768 16B-chunks -> 96B segments
#pragma unroll
    for (int it = 0; it < 3; ++it) {
      int q = it * 256 + t;
      int px = q / 6;
      int chk = q - px * 6;
      union { uint4 u; __hip_bfloat16 h[8]; } v;
#pragma unroll
      for (int i = 0; i < 8; ++i)
        v.h[i] = stage[(chk * 8 + i) * 129 + px];
      *(uint4*)(Hmat + rowbase + (size_t)px * 1248 + j * 96 + c0 + chk * 8) = v.u;
    }
    __syncthreads();
  }
}

// ---------------------------------------------------------------------------
// gemm1 (m97 structure): Y1[m][n] = bf16(relu(Hmat[m][:]*V[n][:]^T + b1e[n]))
// 128x128 tile, BK=32, global_load_lds width-16 into unpadded As/Bs[128][32].
// XCD-swizzled block order: 4 n-tiles of one m-tile stay on one XCD's L2.
// ---------------------------------------------------------------------------
__global__ __launch_bounds__(256) void gemm1_kernel(
    const __hip_bfloat16* __restrict__ A,    // [M][1248]
    const __hip_bfloat16* __restrict__ Bv,   // V [512][1248]
    const float* __restrict__ b1e,
    __hip_bfloat16* __restrict__ Y1)         // [M][512]
{
  const int K = 1248;
  int linear = blockIdx.x;
  int xcd = linear & 7;
  int slot = linear >> 3;
  int mtiles_per_xcd = (int)(gridDim.x >> 5);  // (gridDim.x/4 m-tiles)/8 xcds
  int ntile = slot & 3;
  int mtile = xcd * mtiles_per_xcd + (slot >> 2);
  int m0 = mtile * 128;
  int n0 = ntile * 128;
  int t = threadIdx.x;
  int lane = t & 63, wv = t >> 6;
  int wm = wv & 1, wn = wv >> 1;
  int lr = lane & 15, quad = lane >> 4;

  __shared__ __align__(16) __hip_bfloat16 As[128 * 32];
  __shared__ __align__(16) __hip_bfloat16 Bs[128 * 32];

  // staging: wave wv async-loads row groups {wv*16, (wv+4)*16} of A and B.
  int srow = lane >> 2;
  int scol = (lane & 3) * 8;
  const __hip_bfloat16* gA0 = A + (size_t)(m0 + wv * 16 + srow) * K + scol;
  const __hip_bfloat16* gA1 = A + (size_t)(m0 + (wv + 4) * 16 + srow) * K + scol;
  const __hip_bfloat16* gB0 = Bv + (size_t)(n0 + wv * 16 + srow) * K + scol;
  const __hip_bfloat16* gB1 = Bv + (size_t)(n0 + (wv + 4) * 16 + srow) * K + scol;
  __hip_bfloat16* lA0 = As + (wv * 16) * 32;
  __hip_bfloat16* lA1 = As + ((wv + 4) * 16) * 32;
  __hip_bfloat16* lB0 = Bs + (wv * 16) * 32;
  __hip_bfloat16* lB1 = Bs + ((wv + 4) * 16) * 32;

  f32x4 acc[4][4];
#pragma unroll
  for (int i = 0; i < 4; ++i)
#pragma unroll
    for (int jj = 0; jj < 4; ++jj) acc[i][jj] = (f32x4){0.f, 0.f, 0.f, 0.f};

  for (int k0 = 0; k0 < K; k0 += 32) {
    __syncthreads();  // previous iteration's LDS reads done
    load_lds16(gA0 + k0, lA0);
    load_lds16(gA1 + k0, lA1);
    load_lds16(gB0 + k0, lB0);
    load_lds16(gB1 + k0, lB1);
    __syncthreads();  // staging drained

    bf16x8 af[4], bfr[4];
#pragma unroll
    for (int i = 0; i < 4; ++i)
      af[i] = *(const bf16x8*)(As + (wm * 64 + i * 16 + lr) * 32 + quad * 8);
#pragma unroll
    for (int jj = 0; jj < 4; ++jj)
      bfr[jj] = *(const bf16x8*)(Bs + (wn * 64 + jj * 16 + lr) * 32 + quad * 8);
#pragma unroll
    for (int i = 0; i < 4; ++i)
#pragma unroll
      for (int jj = 0; jj < 4; ++jj)
        acc[i][jj] = __builtin_amdgcn_mfma_f32_16x16x32_bf16(af[i], bfr[jj], acc[i][jj], 0, 0, 0);
  }

  // epilogue: +bias, relu, bf16. C/D: col=lane&15, row=quad*4+reg
#pragma unroll
  for (int jj = 0; jj < 4; ++jj) {
    int n = n0 + wn * 64 + jj * 16 + lr;
    float bias = b1e[n];
#pragma unroll
    for (int i = 0; i < 4; ++i) {
      int mbase = m0 + wm * 64 + i * 16 + quad * 4;
#pragma unroll
      for (int r = 0; r < 4; ++r) {
        float z = acc[i][jj][r] + bias;
        z = z > 0.f ? z : 0.f;
        Y1[(size_t)(mbase + r) * 512 + n] = __float2bfloat16(z);
      }
    }
  }
}

// ---------------------------------------------------------------------------
// gemm2: out[b][o2][p] = W2e[o2][:] * Y1[pix][:] + b2e[o2]; C[o2][pixel]
// computed directly so NCHW stores are coalesced. LDS-free (W2e L2-hot).
// ---------------------------------------------------------------------------
__global__ __launch_bounds__(256) void gemm2_kernel(
    const __hip_bfloat16* __restrict__ Y1,   // [Mpix][512]
    const __hip_bfloat16* __restrict__ W2e,  // [96][512]
    const float* __restrict__ b2e,
    float* __restrict__ out, int b0)
{
  int lane = threadIdx.x & 63, wv = threadIdx.x >> 6;
  int lr = lane & 15, quad = lane >> 4;
  int pw = blockIdx.x * 256 + wv * 64;  // wave's pixel base

  f32x4 acc[6][4];
#pragma unroll
  for (int im = 0; im < 6; ++im)
#pragma unroll
    for (int jn = 0; jn < 4; ++jn) acc[im][jn] = (f32x4){0.f, 0.f, 0.f, 0.f};

  for (int k0 = 0; k0 < 512; k0 += 32) {
    bf16x8 bfrag[4], afrag[6];
#pragma unroll
    for (int jn = 0; jn < 4; ++jn)
      bfrag[jn] = *(const bf16x8*)(Y1 + (size_t)(pw + jn * 16 + lr) * 512 + k0 + quad * 8);
#pragma unroll
    for (int im = 0; im < 6; ++im)
      afrag[im] = *(const bf16x8*)(W2e + (size_t)(im * 16 + lr) * 512 + k0 + quad * 8);
#pragma unroll
    for (int im = 0; im < 6; ++im)
#pragma unroll
      for (int jn = 0; jn < 4; ++jn)
        acc[im][jn] = __builtin_amdgcn_mfma_f32_16x16x32_bf16(afrag[im], bfrag[jn], acc[im][jn], 0, 0, 0);
  }

#pragma unroll
  for (int im = 0; im < 6; ++im) {
#pragma unroll
    for (int r = 0; r < 4; ++r) {
      int o2 = im * 16 + quad * 4 + r;
      float bias = b2e[o2];
#pragma unroll
      for (int jn = 0; jn < 4; ++jn) {
        int p = pw + jn * 16 + lr;
        out[((size_t)(b0 + (p >> 14)) * 96 + o2) * 16384 + (p & 16383)] =
            acc[im][jn][r] + bias;
      }
    }
  }
}

// ---------------------------------------------------------------------------
extern "C" void kernel_launch(void* const* d_in, const int* in_sizes, int n_in,
                              void* d_out, int out_size, void* d_ws, size_t ws_size,
                              hipStream_t stream)
{
  const float* x   = (const float*)d_in[0];
  const float* g1  = (const float*)d_in[1];
  const float* be1 = (const float*)d_in[2];
  const float* mu1 = (const float*)d_in[3];
  const float* va1 = (const float*)d_in[4];
  const float* W1  = (const float*)d_in[5];
  const float* cb1 = (const float*)d_in[6];
  const float* g2  = (const float*)d_in[7];
  const float* be2 = (const float*)d_in[8];
  const float* mu2 = (const float*)d_in[9];
  const float* va2 = (const float*)d_in[10];
  const float* W2  = (const float*)d_in[11];
  const float* cb2 = (const float*)d_in[12];
  float* out = (float*)d_out;

  char* w = (char*)d_ws;
  __hip_bfloat16* V   = (__hip_bfloat16*)w; w += (size_t)512 * 1248 * 2;
  __hip_bfloat16* W2e = (__hip_bfloat16*)w; w += (size_t)96 * 512 * 2;
  float* b1e = (float*)w; w += 2048;
  float* b2e = (float*)w; w += 512;
  size_t fixed = (size_t)(w - (char*)d_ws);

  const size_t satB = (size_t)96 * 17028 * 4;     // per-batch SAT bytes (padded rows)
  const size_t hB   = (size_t)16384 * 1248 * 2;   // per-batch Hmat bytes
  const size_t yB   = (size_t)16384 * 512 * 2;    // per-batch Y1 bytes
  int nb = (ws_size >= fixed + 4 * (satB + hB + yB) + 4096) ? 4 : 1;

  float* SAT = (float*)w; w += (size_t)nb * satB;
  w = (char*)(((uintptr_t)w + 255) & ~(uintptr_t)255);
  __hip_bfloat16* Hm = (__hip_bfloat16*)w; w += (size_t)nb * hB;
  __hip_bfloat16* Y1 = (__hip_bfloat16*)w;

  prep1_kernel<<<512, 256, 0, stream>>>(W1, cb1, g1, be1, mu1, va1, V, b1e);
  prep2_kernel<<<96, 256, 0, stream>>>(W2, cb2, g2, be2, mu2, va2, W2e, b2e);

  for (int b0 = 0; b0 < 4; b0 += nb) {
    sat_kernel<<<nb * 96, 128, 0, stream>>>(x + (size_t)b0 * 96 * 16384, SAT);
    feat_kernel<<<nb * 256, 256, 0, stream>>>(SAT, Hm);
    gemm1_kernel<<<nb * 512, 256, 0, stream>>>(Hm, V, b1e, Y1);
    gemm2_kernel<<<nb * 64, 256, 0, stream>>>(Y1, W2e, b2e, out, b0);
  }
}

// Round 4
// 317.570 us; speedup vs baseline: 1.7454x; 1.0639x over previous
//
#include <hip/hip_runtime.h>
#include <hip/hip_bf16.h>
#include <cstdint>

typedef __attribute__((ext_vector_type(8))) short bf16x8;   // 8 bf16 (4 VGPRs)
typedef __attribute__((ext_vector_type(4))) float f32x4;    // MFMA C/D

#define BN_EPS 1e-5f

// ---------------------------------------------------------------------------
// prep1: fold BN1 + ring telescoping into V (box-feature weights), b1eff.
// ---------------------------------------------------------------------------
__global__ __launch_bounds__(256) void prep1_kernel(
    const float* __restrict__ W1, const float* __restrict__ cb1,
    const float* __restrict__ g1, const float* __restrict__ be1,
    const float* __restrict__ mu1, const float* __restrict__ va1,
    __hip_bfloat16* __restrict__ V, float* __restrict__ b1e)
{
  int o = blockIdx.x;
  int t = threadIdx.x;
  const float* wrow = W1 + (size_t)o * 1248;
  float acc = 0.f;
  for (int i = t; i < 1248; i += 256) {
    float s = g1[i] * rsqrtf(va1[i] + BN_EPS);
    float w = wrow[i];
    acc += w * (be1[i] - mu1[i] * s);
    float g = w * s;
    float gn = 0.f;
    if (i < 1152) {  // has a next-ring partner
      float sn = g1[i + 96] * rsqrtf(va1[i + 96] + BN_EPS);
      gn = wrow[i + 96] * sn;
    }
    V[(size_t)o * 1248 + i] = __float2bfloat16(g - gn);
  }
  for (int d = 32; d > 0; d >>= 1) acc += __shfl_down(acc, d);
  __shared__ float red[4];
  int lane = t & 63, wv = t >> 6;
  if (lane == 0) red[wv] = acc;
  __syncthreads();
  if (t == 0) b1e[o] = cb1[o] + red[0] + red[1] + red[2] + red[3];
}

// ---------------------------------------------------------------------------
// prep2: fold BN2 into W2eff, b2eff.
// ---------------------------------------------------------------------------
__global__ __launch_bounds__(256) void prep2_kernel(
    const float* __restrict__ W2, const float* __restrict__ cb2,
    const float* __restrict__ g2, const float* __restrict__ be2,
    const float* __restrict__ mu2, const float* __restrict__ va2,
    __hip_bfloat16* __restrict__ W2e, float* __restrict__ b2e)
{
  int o = blockIdx.x;
  int t = threadIdx.x;
  const float* wrow = W2 + (size_t)o * 512;
  float acc = 0.f;
  for (int j = t; j < 512; j += 256) {
    float s = g2[j] * rsqrtf(va2[j] + BN_EPS);
    float wv = wrow[j];
    acc += wv * (be2[j] - mu2[j] * s);
    W2e[(size_t)o * 512 + j] = __float2bfloat16(wv * s);
  }
  for (int d = 32; d > 0; d >>= 1) acc += __shfl_down(acc, d);
  __shared__ float red[4];
  int lane = t & 63, wv2 = t >> 6;
  if (lane == 0) red[wv2] = acc;
  __syncthreads();
  if (t == 0) b2e[o] = cb2[o] + red[0] + red[1] + red[2] + red[3];
}

// ---------------------------------------------------------------------------
// sat: one block per (b,c) plane. Exclusive SAT [129][132] (rows padded to
// 132 floats so every row is 16B-aligned for float4 loads in fused1).
// ---------------------------------------------------------------------------
__global__ __launch_bounds__(128) void sat_kernel(
    const float* __restrict__ x, float* __restrict__ SAT)
{
  int plane = blockIdx.x;
  const float* xp = x + (size_t)plane * 16384;
  __shared__ float tile[16384];
  int t = threadIdx.x;
  for (int i = t; i < 16384; i += 128) {
    int r = i >> 7, c = i & 127;
    tile[r * 128 + (c ^ (r & 31))] = xp[i];
  }
  __syncthreads();
  {  // row scan: thread = row
    float run = 0.f;
    int r = t;
    for (int c = 0; c < 128; ++c) {
      int a = r * 128 + (c ^ (r & 31));
      run += tile[a];
      tile[a] = run;
    }
  }
  __syncthreads();
  float* Sg = SAT + (size_t)plane * 17028;  // 129*132
  Sg[t] = 0.f;                   // row 0, cols 0..127
  if (t < 4) Sg[128 + t] = 0.f;  // row 0, cols 128..131
  Sg[(t + 1) * 132] = 0.f;       // col 0, rows 1..128
  float run = 0.f;
  for (int r = 0; r < 128; ++r) {
    run += tile[r * 128 + (t ^ (r & 31))];
    Sg[(r + 1) * 132 + t + 1] = run;
  }
}

// ---------------------------------------------------------------------------
// fused1: feat + gemm1 fused. One block per image row (bL, y): M=128 pixels,
// N=512 outputs, K=1248 (13 rings x 96 ch). Per ring j:
//   E[c][x] = S[y2][x]-S[y1][x] staged in LDS (fp32, float4 L2 reads);
//   3 sub-chunks of K=32: build As[128][40] bf16 (taps = E[x2]-E[x1]),
//   MFMA with A-frags from LDS, B-frags (V rows) straight from global (L2).
// E-fill(j+1) is issued under the last MFMA phase of ring j.
// Y1[m][n] = bf16(relu(acc + b1e[n])). No Hmat intermediate at all.
// ---------------------------------------------------------------------------
__global__ __launch_bounds__(512, 2) void fused1_kernel(
    const float* __restrict__ SAT, const __hip_bfloat16* __restrict__ V,
    const float* __restrict__ b1e, __hip_bfloat16* __restrict__ Y1, int nb)
{
  __shared__ __align__(16) float E[96 * 132];                 // 50688 B
  __shared__ __align__(16) __hip_bfloat16 As[128 * 40];       // 10240 B

  int blk = blockIdx.x;
  int rows_per_xcd = (nb * 128) >> 3;          // consecutive rows per XCD
  int r = (blk & 7) * rows_per_xcd + (blk >> 3);
  int bL = r >> 7, y = r & 127;

  int t = threadIdx.x;
  int lane = t & 63, wv = t >> 6;              // wv 0..7 (wave's 64-col slab)
  int lr = lane & 15, quad = lane >> 4;

  const float* Sb = SAT + (size_t)bL * 96 * 17028;

  // build-task geometry (fixed): thread -> (px, granule g of 8 channels)
  int bpx = t & 127;
  int bg = t >> 7;  // 0..3

  f32x4 acc[8][4];
#pragma unroll
  for (int i = 0; i < 8; ++i)
#pragma unroll
    for (int jn = 0; jn < 4; ++jn) acc[i][jn] = (f32x4){0.f, 0.f, 0.f, 0.f};

  // ---- E-fill for ring j: 96 ch x 33 float4 granules = 3168 tasks ----
  auto efill = [&](int j) {
    int y1 = (y - j < 0) ? 0 : (y - j);
    int y2 = ((y + j > 127) ? 127 : (y + j)) + 1;
    for (int idx = t; idx < 3168; idx += 512) {
      int cl = idx / 33;
      int ck = idx - cl * 33;
      const float* bp = Sb + (size_t)cl * 17028 + ck * 4;
      float4 a = *(const float4*)(bp + y2 * 132);
      float4 b = *(const float4*)(bp + y1 * 132);
      float4 d;
      d.x = a.x - b.x; d.y = a.y - b.y; d.z = a.z - b.z; d.w = a.w - b.w;
      *(float4*)(E + cl * 132 + ck * 4) = d;
    }
  };

  int x1 = 0, x2 = 0;  // set per ring for the build taps
  // ---- build As for (ring j, sub-chunk): 32 channels ----
  auto build = [&](int j, int sub) {
    const float* Eb = E + (sub * 32 + bg * 8) * 132;
    union { bf16x8 v; __hip_bfloat16 h[8]; } pk;
#pragma unroll
    for (int i = 0; i < 8; ++i)
      pk.h[i] = __float2bfloat16(Eb[i * 132 + x2] - Eb[i * 132 + x1]);
    *(bf16x8*)(As + bpx * 40 + bg * 8) = pk.v;
  };

  efill(0);
  __syncthreads();

  for (int j = 0; j < 13; ++j) {
    x1 = (bpx - j < 0) ? 0 : (bpx - j);
    x2 = ((bpx + j > 127) ? 127 : (bpx + j)) + 1;
    for (int sub = 0; sub < 3; ++sub) {
      build(j, sub);
      __syncthreads();
      if (sub == 2 && j < 12) efill(j + 1);  // overlaps MFMA below
      bf16x8 af[8], bfr[4];
#pragma unroll
      for (int i = 0; i < 8; ++i)
        af[i] = *(const bf16x8*)(As + (i * 16 + lr) * 40 + quad * 8);
#pragma unroll
      for (int jn = 0; jn < 4; ++jn)
        bfr[jn] = *(const bf16x8*)(V + (size_t)(wv * 64 + jn * 16 + lr) * 1248
                                   + j * 96 + sub * 32 + quad * 8);
#pragma unroll
      for (int i = 0; i < 8; ++i)
#pragma unroll
        for (int jn = 0; jn < 4; ++jn)
          acc[i][jn] = __builtin_amdgcn_mfma_f32_16x16x32_bf16(af[i], bfr[jn], acc[i][jn], 0, 0, 0);
      __syncthreads();
    }
  }

  // epilogue: +bias, relu, bf16. C/D: col=lane&15 (n), row=quad*4+reg (m)
  size_t mrow = (size_t)bL * 16384 + (size_t)y * 128;
#pragma unroll
  for (int jn = 0; jn < 4; ++jn) {
    int n = wv * 64 + jn * 16 + lr;
    float bias = b1e[n];
#pragma unroll
    for (int i = 0; i < 8; ++i) {
      int pbase = i * 16 + quad * 4;
#pragma unroll
      for (int rr = 0; rr < 4; ++rr) {
        float z = acc[i][jn][rr] + bias;
        z = z > 0.f ? z : 0.f;
        Y1[(mrow + pbase + rr) * 512 + n] = __float2bfloat16(z);
      }
    }
  }
}

// ---------------------------------------------------------------------------
// gemm2: out[b][o2][p] = W2e[o2][:] * Y1[pix][:] + b2e[o2]; C[o2][pixel]
// computed directly so NCHW stores are coalesced. LDS-free (W2e L2-hot).
// ---------------------------------------------------------------------------
__global__ __launch_bounds__(256) void gemm2_kernel(
    const __hip_bfloat16* __restrict__ Y1,   // [Mpix][512]
    const __hip_bfloat16* __restrict__ W2e,  // [96][512]
    const float* __restrict__ b2e,
    float* __restrict__ out, int b0)
{
  int lane = threadIdx.x & 63, wv = threadIdx.x >> 6;
  int lr = lane & 15, quad = lane >> 4;
  int pw = blockIdx.x * 256 + wv * 64;  // wave's pixel base

  f32x4 acc[6][4];
#pragma unroll
  for (int im = 0; im < 6; ++im)
#pragma unroll
    for (int jn = 0; jn < 4; ++jn) acc[im][jn] = (f32x4){0.f, 0.f, 0.f, 0.f};

  for (int k0 = 0; k0 < 512; k0 += 32) {
    bf16x8 bfrag[4], afrag[6];
#pragma unroll
    for (int jn = 0; jn < 4; ++jn)
      bfrag[jn] = *(const bf16x8*)(Y1 + (size_t)(pw + jn * 16 + lr) * 512 + k0 + quad * 8);
#pragma unroll
    for (int im = 0; im < 6; ++im)
      afrag[im] = *(const bf16x8*)(W2e + (size_t)(im * 16 + lr) * 512 + k0 + quad * 8);
#pragma unroll
    for (int im = 0; im < 6; ++im)
#pragma unroll
      for (int jn = 0; jn < 4; ++jn)
        acc[im][jn] = __builtin_amdgcn_mfma_f32_16x16x32_bf16(afrag[im], bfrag[jn], acc[im][jn], 0, 0, 0);
  }

#pragma unroll
  for (int im = 0; im < 6; ++im) {
#pragma unroll
    for (int r = 0; r < 4; ++r) {
      int o2 = im * 16 + quad * 4 + r;
      float bias = b2e[o2];
#pragma unroll
      for (int jn = 0; jn < 4; ++jn) {
        int p = pw + jn * 16 + lr;
        out[((size_t)(b0 + (p >> 14)) * 96 + o2) * 16384 + (p & 16383)] =
            acc[im][jn][r] + bias;
      }
    }
  }
}

// ---------------------------------------------------------------------------
extern "C" void kernel_launch(void* const* d_in, const int* in_sizes, int n_in,
                              void* d_out, int out_size, void* d_ws, size_t ws_size,
                              hipStream_t stream)
{
  const float* x   = (const float*)d_in[0];
  const float* g1  = (const float*)d_in[1];
  const float* be1 = (const float*)d_in[2];
  const float* mu1 = (const float*)d_in[3];
  const float* va1 = (const float*)d_in[4];
  const float* W1  = (const float*)d_in[5];
  const float* cb1 = (const float*)d_in[6];
  const float* g2  = (const float*)d_in[7];
  const float* be2 = (const float*)d_in[8];
  const float* mu2 = (const float*)d_in[9];
  const float* va2 = (const float*)d_in[10];
  const float* W2  = (const float*)d_in[11];
  const float* cb2 = (const float*)d_in[12];
  float* out = (float*)d_out;

  char* w = (char*)d_ws;
  __hip_bfloat16* V   = (__hip_bfloat16*)w; w += (size_t)512 * 1248 * 2;
  __hip_bfloat16* W2e = (__hip_bfloat16*)w; w += (size_t)96 * 512 * 2;
  float* b1e = (float*)w; w += 2048;
  float* b2e = (float*)w; w += 512;
  size_t fixed = (size_t)(w - (char*)d_ws);

  const size_t satB = (size_t)96 * 17028 * 4;     // per-batch SAT bytes
  const size_t yB   = (size_t)16384 * 512 * 2;    // per-batch Y1 bytes
  int nb = (ws_size >= fixed + 4 * (satB + yB) + 4096) ? 4 : 1;

  float* SAT = (float*)w; w += (size_t)nb * satB;
  w = (char*)(((uintptr_t)w + 255) & ~(uintptr_t)255);
  __hip_bfloat16* Y1 = (__hip_bfloat16*)w;

  prep1_kernel<<<512, 256, 0, stream>>>(W1, cb1, g1, be1, mu1, va1, V, b1e);
  prep2_kernel<<<96, 256, 0, stream>>>(W2, cb2, g2, be2, mu2, va2, W2e, b2e);

  for (int b0 = 0; b0 < 4; b0 += nb) {
    sat_kernel<<<nb * 96, 128, 0, stream>>>(x + (size_t)b0 * 96 * 16384, SAT);
    fused1_kernel<<<nb * 128, 512, 0, stream>>>(SAT, V, b1e, Y1, nb);
    gemm2_kernel<<<nb * 64, 256, 0, stream>>>(Y1, W2e, b2e, out, b0);
  }
}